// Round 1
// baseline (4198.516 us; speedup 1.0000x reference)
//
#include <hip/hip_runtime.h>
#include <math.h>

#define H 32
#define LAGN 50

__device__ __forceinline__ float sigmoidf_(float x){
  return 1.0f/(1.0f + __expf(-x));
}
__device__ __forceinline__ float tanhf_(float x){
  // (e^{2x}-1)/(e^{2x}+1) computed stably for both tails
  float e = __expf(2.0f*x);
  return 1.0f - 2.0f/(e + 1.0f);
}

// ---------------- LSTM + time-attention + fc, one thread per node ----------
__global__ __launch_bounds__(256) void k_lstm(
    const float* __restrict__ yx,    // [N,50]
    const float* __restrict__ w_ih,  // [128]
    const float* __restrict__ w_hh,  // [128,32]
    const float* __restrict__ b_ih,  // [128]
    const float* __restrict__ b_hh,  // [128]
    const float* __restrict__ att_W, // [50,32]
    const float* __restrict__ fc_W,  // [32,32]
    const float* __restrict__ fc_b,  // [32]
    float* __restrict__ x1,          // [N,32] out
    int N)
{
  int n = blockIdx.x*blockDim.x + threadIdx.x;
  if (n >= N) return;

  float h[H], c[H], S[H];
  #pragma unroll
  for (int j=0;j<H;j++){ h[j]=0.f; c[j]=0.f; S[j]=0.f; }
  float m = -1e30f, Z = 0.f;

  const float* yxr = yx + (size_t)n*LAGN;

  #pragma unroll 1
  for (int t=0;t<LAGN;t++){
    float xt = yxr[t];
    float hn[H];
    float st = 0.f;
    #pragma unroll
    for (int j=0;j<H;j++){
      float ai = b_ih[0*H+j] + b_hh[0*H+j] + w_ih[0*H+j]*xt;
      float af = b_ih[1*H+j] + b_hh[1*H+j] + w_ih[1*H+j]*xt;
      float ag = b_ih[2*H+j] + b_hh[2*H+j] + w_ih[2*H+j]*xt;
      float ao = b_ih[3*H+j] + b_hh[3*H+j] + w_ih[3*H+j]*xt;
      #pragma unroll
      for (int k=0;k<H;k++){
        float hk = h[k];
        ai += w_hh[(0*H+j)*H+k]*hk;
        af += w_hh[(1*H+j)*H+k]*hk;
        ag += w_hh[(2*H+j)*H+k]*hk;
        ao += w_hh[(3*H+j)*H+k]*hk;
      }
      float iv = sigmoidf_(ai);
      float fv = sigmoidf_(af);
      float gv = tanhf_(ag);
      float ov = sigmoidf_(ao);
      float cv = fv*c[j] + iv*gv;
      c[j] = cv;
      float hv = ov*tanhf_(cv);
      hn[j] = hv;
      st += hv * att_W[t*H+j];
    }
    // online softmax over t (exact, flash-style)
    float mn = fmaxf(m, st);
    float sc = __expf(m - mn);
    float p  = __expf(st - mn);
    Z = Z*sc + p;
    #pragma unroll
    for (int j=0;j<H;j++){
      S[j] = S[j]*sc + p*hn[j];
      h[j] = hn[j];
    }
    m = mn;
  }

  float invZ = 1.0f/Z;
  #pragma unroll
  for (int j=0;j<H;j++) S[j] *= invZ;   // pooled

  float* xo = x1 + (size_t)n*H;
  #pragma unroll
  for (int jj=0;jj<H;jj++){
    float a = fc_b[jj];
    #pragma unroll
    for (int k=0;k<H;k++) a += S[k]*fc_W[k*H+jj];
    xo[jj] = fmaxf(a, 0.f);
  }
}

// ---------------- GCN helpers ------------------------------------------------
__global__ void k_deg_init(float* __restrict__ deg, int N){
  int i = blockIdx.x*blockDim.x + threadIdx.x;
  if (i < N) deg[i] = 1.0f;   // self-loop weight
}

__global__ void k_deg_edges(const int* __restrict__ ei, const float* __restrict__ ew,
                            float* __restrict__ deg, int E){
  int e = blockIdx.x*blockDim.x + threadIdx.x;
  if (e < E) atomicAdd(&deg[ei[E+e]], ew[e]);   // dst row = ei[1]
}

__global__ void k_dis(float* __restrict__ deg, int N){
  int i = blockIdx.x*blockDim.x + threadIdx.x;
  if (i < N) deg[i] = 1.0f/sqrtf(deg[i]);       // deg >= 1 always
}

__global__ void k_norm(const int* __restrict__ ei, const float* __restrict__ ew,
                       const float* __restrict__ dis, float* __restrict__ nrm, int E){
  int e = blockIdx.x*blockDim.x + threadIdx.x;
  if (e < E) nrm[e] = dis[ei[e]]*ew[e]*dis[ei[E+e]];
}

// xw = x @ W ; out = (1/deg)*xw + b   (self-loop contribution folded in)
__global__ __launch_bounds__(256) void k_xw(
    const float* __restrict__ x, const float* __restrict__ W,
    const float* __restrict__ b, const float* __restrict__ dis,
    float* __restrict__ xw, float* __restrict__ out, int N)
{
  int n = blockIdx.x*blockDim.x + threadIdx.x;
  if (n >= N) return;
  float xv[H];
  const float4* xr = (const float4*)(x + (size_t)n*H);
  #pragma unroll
  for (int q=0;q<H/4;q++){
    float4 v = xr[q];
    xv[4*q+0]=v.x; xv[4*q+1]=v.y; xv[4*q+2]=v.z; xv[4*q+3]=v.w;
  }
  float d = dis[n];
  float sn = d*d;               // = 1/deg
  float* xwr = xw + (size_t)n*H;
  float* outr = out + (size_t)n*H;
  #pragma unroll
  for (int j=0;j<H;j++){
    float a = 0.f;
    #pragma unroll
    for (int k=0;k<H;k++) a += xv[k]*W[k*H+j];
    xwr[j]  = a;
    outr[j] = sn*a + b[j];
  }
}

// out[dst] += norm[e] * xw[src] ; 8 threads per edge, 4 channels each
__global__ __launch_bounds__(256) void k_edge(
    const int* __restrict__ ei, const float* __restrict__ nrm,
    const float* __restrict__ xw, float* __restrict__ out, int E)
{
  int tid = blockIdx.x*blockDim.x + threadIdx.x;
  int e = tid >> 3;
  if (e >= E) return;
  int q = (tid & 7) * 4;
  int s = ei[e];
  int d = ei[E+e];
  float nm = nrm[e];
  float4 v = *(const float4*)(xw + (size_t)s*H + q);
  float* o = out + (size_t)d*H + q;
  atomicAdd(o+0, nm*v.x);
  atomicAdd(o+1, nm*v.y);
  atomicAdd(o+2, nm*v.z);
  atomicAdd(o+3, nm*v.w);
}

__global__ void k_final(const float* __restrict__ x2, const float* __restrict__ nx,
                        const float* __restrict__ lw, const float* __restrict__ lb,
                        float* __restrict__ out, int N)
{
  int n = blockIdx.x*blockDim.x + threadIdx.x;
  if (n >= N) return;
  float a = lb[0];
  const float* xr = x2 + (size_t)n*H;
  #pragma unroll
  for (int j=0;j<H;j++) a += xr[j]*lw[j];
  const float* nr = nx + (size_t)n*4;
  #pragma unroll
  for (int f=0;f<4;f++) a += nr[f]*lw[H+f];
  out[n] = fmaxf(a, 0.f);
}

extern "C" void kernel_launch(void* const* d_in, const int* in_sizes, int n_in,
                              void* d_out, int out_size, void* d_ws, size_t ws_size,
                              hipStream_t stream) {
  const float* node_x   = (const float*)d_in[0];
  const float* node_yx  = (const float*)d_in[1];
  const int*   edge_idx = (const int*)  d_in[2];
  const float* edge_w   = (const float*)d_in[3];
  const float* w_ih     = (const float*)d_in[4];
  const float* w_hh     = (const float*)d_in[5];
  const float* b_ih     = (const float*)d_in[6];
  const float* b_hh     = (const float*)d_in[7];
  const float* att_W    = (const float*)d_in[8];
  const float* fc_W     = (const float*)d_in[9];
  const float* fc_b     = (const float*)d_in[10];
  const float* gcn1_W   = (const float*)d_in[11];
  const float* gcn1_b   = (const float*)d_in[12];
  const float* gcn2_W   = (const float*)d_in[13];
  const float* gcn2_b   = (const float*)d_in[14];
  const float* lin_W    = (const float*)d_in[15];
  const float* lin_b    = (const float*)d_in[16];
  float* out = (float*)d_out;

  int N = in_sizes[0] / 4;     // node_x is [N,4]
  int E = in_sizes[3];         // edge_weight is [E]

  float* ws = (float*)d_ws;
  float* x1  = ws;                       // [N,32]  (reused as out2)
  float* xw  = ws + (size_t)N*H;         // [N,32]
  float* o1  = ws + 2*(size_t)N*H;       // [N,32]
  float* deg = ws + 3*(size_t)N*H;       // [N]   (becomes dis)
  float* nrm = deg + N;                  // [E]

  dim3 blk(256);
  int gN  = (N + 255) / 256;
  int gE  = (E + 255) / 256;
  int gE8 = (int)(((size_t)E*8 + 255) / 256);

  // 1. LSTM + attention + fc
  k_lstm<<<gN, blk, 0, stream>>>(node_yx, w_ih, w_hh, b_ih, b_hh,
                                 att_W, fc_W, fc_b, x1, N);
  // 2. degrees (self-loop = 1.0 init), then dis = deg^-1/2, then edge norms
  k_deg_init<<<gN, blk, 0, stream>>>(deg, N);
  k_deg_edges<<<gE, blk, 0, stream>>>(edge_idx, edge_w, deg, E);
  k_dis<<<gN, blk, 0, stream>>>(deg, N);
  k_norm<<<gE, blk, 0, stream>>>(edge_idx, edge_w, deg, nrm, E);
  // 3. GCN layer 1
  k_xw  <<<gN, blk, 0, stream>>>(x1, gcn1_W, gcn1_b, deg, xw, o1, N);
  k_edge<<<gE8, blk, 0, stream>>>(edge_idx, nrm, xw, o1, E);
  // 4. GCN layer 2 (out2 overwrites x1 buffer)
  k_xw  <<<gN, blk, 0, stream>>>(o1, gcn2_W, gcn2_b, deg, xw, x1, N);
  k_edge<<<gE8, blk, 0, stream>>>(edge_idx, nrm, xw, x1, E);
  // 5. final linear + relu
  k_final<<<gN, blk, 0, stream>>>(x1, node_x, lin_W, lin_b, out, N);
}